// Round 4
// baseline (160.386 us; speedup 1.0000x reference)
//
#include <hip/hip_runtime.h>
#include <math.h>

#define NN 32
#define PI_F 3.14159265358979323846f

// d_ws layout (floats):
//   [0..32)     va2pi = 2*pi*5*sigmoid(v)
//   [32..64)    K1 = 0.25*ca^2*ba      (rdd = K1 + K2*r + K3*rd)
//   [64..96)    K2 = -0.25*ca^2
//   [96..128)   K3 = -ca
//   [128..1152) A row-major 32x32 = w_a*cos(phi_a), zero diag
//   [1152..2176)B row-major 32x32 = w_a*sin(phi_a), zero diag
__global__ void precompute_kernel(const float* __restrict__ v,
                                  const float* __restrict__ b,
                                  const float* __restrict__ c,
                                  const float* __restrict__ w,
                                  const float* __restrict__ phi,
                                  float* __restrict__ ws) {
    const int t = threadIdx.x;  // 0..1023
    // _zero_diag: flat t -> 0 if t%33==0 (diag + last), else param[t/33][t%33-1]
    float A = 0.f, B = 0.f;
    const int rem = t % 33;
    if (rem != 0) {
        const int a = t / 33;
        const float wa = 1.0f / (1.0f + __expf(-w[a * NN + rem - 1]));            // W_MAX=1
        const float pa = (2.0f * PI_F) / (1.0f + __expf(-phi[a * NN + rem - 1])); // PHI_MAX=2pi
        float sp, cp; __sincosf(pa, &sp, &cp);
        A = wa * cp; B = wa * sp;
    }
    ws[128 + t] = A;
    ws[1152 + t] = B;
    if (t < NN) {
        ws[t] = 2.0f * PI_F * 5.0f / (1.0f + __expf(-v[t]));
    } else if (t < 2 * NN) {
        const int i = t - NN;
        const float ba = 2.0f  / (1.0f + __expf(-b[i]));
        // K1 needs ca too; compute both here (cheap redundant exp)
        const float ca = 10.0f / (1.0f + __expf(-c[i]));
        ws[32 + i] = 0.25f * ca * ca * ba;
    } else if (t < 3 * NN) {
        const int i = t - 2 * NN;
        const float ca = 10.0f / (1.0f + __expf(-c[i]));
        ws[64 + i] = -0.25f * ca * ca;
        ws[96 + i] = -ca;
    }
}

// Sliced transposed layout: block = 64 elements x 4 slice-waves.
//   lane (0..63) -> element e = blockIdx*64 + lane (whole element in registers)
//   wave s (0..3) -> output rows 8s..8s+7
// Phase A (per wave, 4x duplicated): u_j = r_j sin(psi_j), v_j = r_j cos(psi_j)
//   for all 32 j -> pure register arrays, no LDS, no barriers.
// Phase B: rows i in slice: P_i = sum_j (A_ij u_j - B_ij v_j),
//   Q_i = sum_j (A_ij v_j + B_ij u_j); A/B fetched with WAVE-UNIFORM addresses
//   (row index readfirstlane'd) -> scalar s_load on the SMEM pipe, phase B is
//   almost pure v_fmac. psi_dot_i = va2pi_i + c_i P_i - s_i Q_i.
__global__ __launch_bounds__(256, 4)
void hopf_kernel(const float* __restrict__ states,
                 const float* __restrict__ ws,
                 float* __restrict__ out,
                 const int Btot) {
    const int lane = threadIdx.x & 63;
    const int s    = __builtin_amdgcn_readfirstlane(threadIdx.x >> 6);  // slice 0..3

    const int e = blockIdx.x * 64 + lane;
    if (e >= Btot) return;

    const float4* s4 = (const float4*)(states + (size_t)e * 96);
    float4*       o4 = (float4*)(out + (size_t)e * 96);

    // slice-row data (issued early; overlaps phase A): psi/r/rd of rows 8s..8s+7
    const float4 psiA = s4[2 * s],      psiB = s4[2 * s + 1];
    const float4 rA   = s4[8 + 2 * s],  rB   = s4[8 + 2 * s + 1];
    const float4 rdA  = s4[16 + 2 * s], rdB  = s4[16 + 2 * s + 1];

    // ---- phase A: u,v for all 32 oscillators of this element ----
    float u[NN], v[NN];
#pragma unroll
    for (int k = 0; k < 8; ++k) {
        const float4 p4 = s4[k];
        const float4 r4 = s4[8 + k];
        float sn, cs;
        __sincosf(p4.x, &sn, &cs); u[4*k+0] = r4.x * sn; v[4*k+0] = r4.x * cs;
        __sincosf(p4.y, &sn, &cs); u[4*k+1] = r4.y * sn; v[4*k+1] = r4.y * cs;
        __sincosf(p4.z, &sn, &cs); u[4*k+2] = r4.z * sn; v[4*k+2] = r4.z * cs;
        __sincosf(p4.w, &sn, &cs); u[4*k+3] = r4.w * sn; v[4*k+3] = r4.w * cs;
    }

    // ---- r_d passthrough + r_d_dot for slice rows (K's are wave-uniform s_loads)
    {
        float4 ddA, ddB;
        const float* K1 = ws + 32 + 8 * s;
        const float* K2 = ws + 64 + 8 * s;
        const float* K3 = ws + 96 + 8 * s;
        ddA.x = fmaf(K2[0], rA.x, fmaf(K3[0], rdA.x, K1[0]));
        ddA.y = fmaf(K2[1], rA.y, fmaf(K3[1], rdA.y, K1[1]));
        ddA.z = fmaf(K2[2], rA.z, fmaf(K3[2], rdA.z, K1[2]));
        ddA.w = fmaf(K2[3], rA.w, fmaf(K3[3], rdA.w, K1[3]));
        ddB.x = fmaf(K2[4], rB.x, fmaf(K3[4], rdB.x, K1[4]));
        ddB.y = fmaf(K2[5], rB.y, fmaf(K3[5], rdB.y, K1[5]));
        ddB.z = fmaf(K2[6], rB.z, fmaf(K3[6], rdB.z, K1[6]));
        ddB.w = fmaf(K2[7], rB.w, fmaf(K3[7], rdB.w, K1[7]));
        o4[8 + 2 * s]  = rdA;   // r_d passthrough
        o4[8 + 2 * s + 1] = rdB;
        o4[16 + 2 * s] = ddA;   // r_d_dot
        o4[16 + 2 * s + 1] = ddB;
    }

    // ---- phase B: 8 coupling rows, A/B rows via scalar loads ----
    float4 odA, odB;
#pragma unroll
    for (int ii = 0; ii < 8; ++ii) {
        const int i = 8 * s + ii;                    // wave-uniform row index
        const float* __restrict__ Ar = ws + 128  + i * NN;
        const float* __restrict__ Br = ws + 1152 + i * NN;
        float P0 = 0.f, P1 = 0.f, Q0 = 0.f, Q1 = 0.f;
#pragma unroll
        for (int j = 0; j < NN; j += 2) {
            const float a0 = Ar[j],     b0 = Br[j];
            const float a1 = Ar[j + 1], b1 = Br[j + 1];
            P0 = fmaf(a0,  u[j],     P0);
            P0 = fmaf(-b0, v[j],     P0);
            Q0 = fmaf(a0,  v[j],     Q0);
            Q0 = fmaf(b0,  u[j],     Q0);
            P1 = fmaf(a1,  u[j + 1], P1);
            P1 = fmaf(-b1, v[j + 1], P1);
            Q1 = fmaf(a1,  v[j + 1], Q1);
            Q1 = fmaf(b1,  u[j + 1], Q1);
        }
        const float P = P0 + P1;
        const float Q = Q0 + Q1;
        const float psi_i = (ii < 4)
            ? ((ii == 0) ? psiA.x : (ii == 1) ? psiA.y : (ii == 2) ? psiA.z : psiA.w)
            : ((ii == 4) ? psiB.x : (ii == 5) ? psiB.y : (ii == 6) ? psiB.z : psiB.w);
        float si, ci; __sincosf(psi_i, &si, &ci);
        const float va = ws[i];                      // wave-uniform
        const float val = fmaf(ci, P, fmaf(-si, Q, va));
        if (ii < 4) ((float*)&odA)[ii] = val; else ((float*)&odB)[ii - 4] = val;
    }
    o4[2 * s]     = odA;   // psi_dot rows 8s..8s+3
    o4[2 * s + 1] = odB;   // psi_dot rows 8s+4..8s+7
}

extern "C" void kernel_launch(void* const* d_in, const int* in_sizes, int n_in,
                              void* d_out, int out_size, void* d_ws, size_t ws_size,
                              hipStream_t stream) {
    const float* states = (const float*)d_in[0];
    const float* v      = (const float*)d_in[1];
    const float* b      = (const float*)d_in[2];
    const float* c      = (const float*)d_in[3];
    const float* w      = (const float*)d_in[4];
    const float* phi    = (const float*)d_in[5];
    float* out = (float*)d_out;
    float* ws  = (float*)d_ws;

    const int B = in_sizes[0] / 96;            // 65536
    precompute_kernel<<<1, 1024, 0, stream>>>(v, b, c, w, phi, ws);

    const int blocks = (B + 63) / 64;          // 1024 blocks x 4 waves = 4 waves/SIMD
    hopf_kernel<<<blocks, 256, 0, stream>>>(states, ws, out, B);
}

// Round 6
// 95.078 us; speedup vs baseline: 1.6869x; 1.6869x over previous
//
#include <hip/hip_runtime.h>
#include <math.h>

#define NN 32
#define PI_F 3.14159265358979323846f

typedef _Float16 h2  __attribute__((ext_vector_type(2)));   // fdot2 operand type
typedef __fp16   fp2 __attribute__((ext_vector_type(2)));   // cvt_pkrtz result type

__device__ __forceinline__ h2 as_h2(int x) {
    union { int i; h2 h; } u; u.i = x; return u.h;
}
__device__ __forceinline__ int pack_rtz(float a, float b) {
    union { fp2 h; int i; } u;
    u.h = __builtin_amdgcn_cvt_pkrtz(a, b);
    return u.i;
}

// d_ws layout (uint words):
//   [0..1024)    Wp[i*32+j] = half2{ A_ij, -B_ij }   A=w_a cos(phi_a), B=w_a sin(phi_a), zero diag
//   [1024..2048) Wq[i*32+j] = half2{ B_ij,  A_ij }
//   as float:
//   [2048..2080) va2pi = 2*pi*5*sigmoid(v)
//   [2080..2112) K1 = 0.25*ca^2*ba     (rdd = K1 + K2*r + K3*rd)
//   [2112..2144) K2 = -0.25*ca^2
//   [2144..2176) K3 = -ca
__global__ void precompute_kernel(const float* __restrict__ v,
                                  const float* __restrict__ b,
                                  const float* __restrict__ c,
                                  const float* __restrict__ w,
                                  const float* __restrict__ phi,
                                  unsigned* __restrict__ wsu) {
    const int t = threadIdx.x;  // 0..1023 = 32*i + j
    // _zero_diag: flat t -> 0 if t%33==0, else param[t/33][t%33-1]
    float A = 0.f, B = 0.f;
    const int rem = t % 33;
    if (rem != 0) {
        const int a = t / 33;
        const float wa = 1.0f / (1.0f + __expf(-w[a * NN + rem - 1]));            // W_MAX=1
        const float pa = (2.0f * PI_F) / (1.0f + __expf(-phi[a * NN + rem - 1])); // PHI_MAX=2pi
        float sp, cp; __sincosf(pa, &sp, &cp);
        A = wa * cp; B = wa * sp;
    }
    wsu[t]        = (unsigned)pack_rtz(A, -B);   // Wp
    wsu[1024 + t] = (unsigned)pack_rtz(B,  A);   // Wq
    float* wsf = (float*)wsu;
    if (t < NN) {
        wsf[2048 + t] = 2.0f * PI_F * 5.0f / (1.0f + __expf(-v[t]));
    } else if (t < 2 * NN) {
        const int i = t - NN;
        const float ba = 2.0f  / (1.0f + __expf(-b[i]));
        const float ca = 10.0f / (1.0f + __expf(-c[i]));
        wsf[2080 + i] = 0.25f * ca * ca * ba;    // K1
    } else if (t < 3 * NN) {
        const int i = t - 2 * NN;
        const float ca = 10.0f / (1.0f + __expf(-c[i]));
        wsf[2112 + i] = -0.25f * ca * ca;        // K2
        wsf[2144 + i] = -ca;                     // K3
    }
}

// Coalesced layout (R2 dataflow): wave = 2 batch elements, lane = oscillator.
//   All global loads/stores: 4 B/lane, 64 lanes contiguous -> 256 B full lines.
//   Exchange: lane packs {u_i,v_i} into one half2 (ds_write_b32), reads all 32
//   back with 8 broadcast ds_read_b128 per pair (half-wave uniform address).
//   Inner loop: 64 v_dot2_f32_f16 (f16 mul, fp32 accumulate).
__global__ __launch_bounds__(256, 4)
void hopf_kernel(const float* __restrict__ states,
                 const unsigned* __restrict__ wsu,
                 float* __restrict__ out,
                 const int npairs) {
    // 4 waves * 2 slices; 36 uints = 144 B slice stride (16B-aligned for b128)
    __shared__ __align__(16) unsigned uvpk[8][36];

    const int tid   = threadIdx.x;
    const int i     = tid & 31;          // oscillator index
    const int slice = tid >> 5;          // 0..7
    const int half  = slice & 1;

    // W rows of oscillator i -> registers (16 dwordx4, L2-served, once)
    int Wp[NN], Wq[NN];
    {
        const int4* rp = (const int4*)(wsu + NN * i);
        const int4* rq = (const int4*)(wsu + 1024 + NN * i);
#pragma unroll
        for (int k = 0; k < 8; ++k) {
            const int4 a = rp[k], b = rq[k];
            Wp[4*k+0] = a.x; Wp[4*k+1] = a.y; Wp[4*k+2] = a.z; Wp[4*k+3] = a.w;
            Wq[4*k+0] = b.x; Wq[4*k+1] = b.y; Wq[4*k+2] = b.z; Wq[4*k+3] = b.w;
        }
    }
    const float* wsf = (const float*)wsu;
    const float va2pi = wsf[2048 + i];
    const float K1    = wsf[2080 + i];
    const float K2    = wsf[2112 + i];
    const float K3    = wsf[2144 + i];

    const int gwave  = (blockIdx.x * blockDim.x + tid) >> 6;
    const int nwaves = (gridDim.x * blockDim.x) >> 6;

    int p = gwave;
    float c_psi = 0.f, c_r = 0.f, c_rd = 0.f;
    if (p < npairs) {
        const int base = (2 * p + half) * 96 + i;
        c_psi = states[base];
        c_r   = states[base + 32];
        c_rd  = states[base + 64];
    }

    for (; p < npairs; p += nwaves) {
        // prefetch next pair BEFORE any memory clobber of this iteration
        const int pn = p + nwaves;
        float n_psi = 0.f, n_r = 0.f, n_rd = 0.f;
        if (pn < npairs) {
            const int nb = (2 * pn + half) * 96 + i;
            n_psi = states[nb];
            n_r   = states[nb + 32];
            n_rd  = states[nb + 64];
        }

        float s, cc;
        __sincosf(c_psi, &s, &cc);
        const float rdd = fmaf(K2, c_r, fmaf(K3, c_rd, K1));

        // publish packed {u,v}; wave-synchronous (in-order DS pipe, disjoint slices)
        uvpk[slice][i] = (unsigned)pack_rtz(c_r * s, c_r * cc);
        __builtin_amdgcn_wave_barrier();
        __asm__ volatile("" ::: "memory");

        float P = 0.f, Q = 0.f;
        const int4* q4p = (const int4*)(&uvpk[slice][0]);
#pragma unroll
        for (int jj = 0; jj < 8; ++jj) {
            const int4 q = q4p[jj];          // {uv_4jj .. uv_4jj+3}, broadcast
            const int j0 = 4 * jj;
            P = __builtin_amdgcn_fdot2(as_h2(q.x), as_h2(Wp[j0+0]), P, false);
            Q = __builtin_amdgcn_fdot2(as_h2(q.x), as_h2(Wq[j0+0]), Q, false);
            P = __builtin_amdgcn_fdot2(as_h2(q.y), as_h2(Wp[j0+1]), P, false);
            Q = __builtin_amdgcn_fdot2(as_h2(q.y), as_h2(Wq[j0+1]), Q, false);
            P = __builtin_amdgcn_fdot2(as_h2(q.z), as_h2(Wp[j0+2]), P, false);
            Q = __builtin_amdgcn_fdot2(as_h2(q.z), as_h2(Wq[j0+2]), Q, false);
            P = __builtin_amdgcn_fdot2(as_h2(q.w), as_h2(Wp[j0+3]), P, false);
            Q = __builtin_amdgcn_fdot2(as_h2(q.w), as_h2(Wq[j0+3]), Q, false);
        }
        __builtin_amdgcn_wave_barrier();
        __asm__ volatile("" ::: "memory");

        const int ob = (2 * p + half) * 96 + i;
        out[ob]      = fmaf(cc, P, fmaf(-s, Q, va2pi));  // psi_dot
        out[ob + 32] = c_rd;                             // r_d passthrough
        out[ob + 64] = rdd;                              // r_d_dot

        c_psi = n_psi; c_r = n_r; c_rd = n_rd;
    }
}

extern "C" void kernel_launch(void* const* d_in, const int* in_sizes, int n_in,
                              void* d_out, int out_size, void* d_ws, size_t ws_size,
                              hipStream_t stream) {
    const float* states = (const float*)d_in[0];
    const float* v      = (const float*)d_in[1];
    const float* b      = (const float*)d_in[2];
    const float* c      = (const float*)d_in[3];
    const float* w      = (const float*)d_in[4];
    const float* phi    = (const float*)d_in[5];
    float* out = (float*)d_out;
    unsigned* wsu = (unsigned*)d_ws;

    const int B = in_sizes[0] / 96;            // 65536
    const int npairs = B / 2;                  // 32768

    precompute_kernel<<<1, 1024, 0, stream>>>(v, b, c, w, phi, wsu);

    // 1024 blocks * 4 waves = 4096 waves = 4 waves/SIMD; 8 pairs/wave
    hopf_kernel<<<1024, 256, 0, stream>>>(states, wsu, out, npairs);
}

// Round 7
// 93.486 us; speedup vs baseline: 1.7156x; 1.0170x over previous
//
#include <hip/hip_runtime.h>
#include <math.h>

#define NN 32
#define PI_F 3.14159265358979323846f

typedef __fp16   fp2 __attribute__((ext_vector_type(2)));   // cvt_pkrtz result type
typedef _Float16 h2  __attribute__((ext_vector_type(2)));   // fdot2 operand type

__device__ __forceinline__ h2 as_h2(unsigned x) {
    union { unsigned u; h2 h; } z; z.u = x; return z.h;
}
__device__ __forceinline__ unsigned pack_rtz(float a, float b) {
    union { fp2 h; unsigned u; } z;
    z.h = __builtin_amdgcn_cvt_pkrtz(a, b);
    return z.u;
}

// Single fused kernel. Wave = 2 batch elements (lanes 0-31 / 32-63), lane =
// oscillator i of its element. NO barriers / NO LDS in the steady loop:
//   - u_i,v_i packed to one f16x2 word; all 32 {u_j,v_j} gathered with
//     ds_bpermute (pure cross-lane register dataflow, wave-synchronous)
//   - inner loop: 64 v_dot2_f32_f16 against per-lane W rows (f16, registers)
//   - distance-2 global prefetch pipelines HBM latency across iterations
//   - W = zero-diag {A=w_a cos(phi_a), B=w_a sin(phi_a)} computed once per
//     block via padded-LDS staging prologue (stride 33, conflict-free)
__global__ __launch_bounds__(256, 4)
void hopf_kernel(const float* __restrict__ states,
                 const float* __restrict__ vP,
                 const float* __restrict__ bP,
                 const float* __restrict__ cP,
                 const float* __restrict__ wP,
                 const float* __restrict__ phiP,
                 float* __restrict__ out,
                 const int npairs) {
    __shared__ unsigned Wp_s[NN * 33];   // {A,-B} packed f16x2, +1 pad
    __shared__ unsigned Wq_s[NN * 33];   // {B, A}

    const int tid      = threadIdx.x;
    const int i        = tid & 31;              // oscillator index
    const int half     = (tid >> 5) & 1;        // element half of the wave
    const int permbase = (tid & 32) * 4;        // byte index of lane 32*half

    const int gwave = (blockIdx.x * blockDim.x + tid) >> 6;
    const int nw    = (gridDim.x * blockDim.x) >> 6;

    // ---- early loads: pipeline stages p and p+nw (latency hidden under prologue)
    int p = gwave;
    float psi0 = 0.f, r0 = 0.f, rd0 = 0.f, psi1 = 0.f, r1 = 0.f, rd1 = 0.f;
    if (p < npairs) {
        const int b0 = (2 * p + half) * 96 + i;
        psi0 = states[b0]; r0 = states[b0 + 32]; rd0 = states[b0 + 64];
    }
    if (p + nw < npairs) {
        const int b1 = (2 * (p + nw) + half) * 96 + i;
        psi1 = states[b1]; r1 = states[b1 + 32]; rd1 = states[b1 + 64];
    }

    // ---- per-lane activations ----
    const float va2pi = 2.f * PI_F * 5.f / (1.f + __expf(-vP[i]));
    const float ba    = 2.f  / (1.f + __expf(-bP[i]));
    const float ca    = 10.f / (1.f + __expf(-cP[i]));
    const float K1 = 0.25f * ca * ca * ba;   // rdd = K1 + K2*r + K3*rd
    const float K2 = -0.25f * ca * ca;
    const float K3 = -ca;

    // ---- W matrices (zero-diag) into LDS, once per block ----
    for (int t = tid; t < NN * NN; t += 256) {
        // _zero_diag: flat t -> 0 if t%33==0, else param[t/33][t%33-1]
        float A = 0.f, Bv = 0.f;
        const int rem = t % 33;
        if (rem != 0) {
            const int a = t / 33;
            const float wa = 1.f / (1.f + __expf(-wP[a * NN + rem - 1]));            // W_MAX=1
            const float pa = 2.f * PI_F / (1.f + __expf(-phiP[a * NN + rem - 1]));   // PHI_MAX=2pi
            float sp, cp; __sincosf(pa, &sp, &cp);
            A = wa * cp; Bv = wa * sp;
        }
        Wp_s[(t >> 5) * 33 + (t & 31)] = pack_rtz(A, -Bv);
        Wq_s[(t >> 5) * 33 + (t & 31)] = pack_rtz(Bv,  A);
    }
    __syncthreads();

    // row i -> registers (stride-33 b32 reads, conflict-free, one-time)
    unsigned Wp[NN], Wq[NN];
#pragma unroll
    for (int j = 0; j < NN; ++j) { Wp[j] = Wp_s[i * 33 + j]; Wq[j] = Wq_s[i * 33 + j]; }

    // ---- main loop: barrier-free ----
    for (; p < npairs; p += nw) {
        // prefetch pair p+2*nw (distance 2; nothing in the loop drains vmcnt)
        const int p2 = p + 2 * nw;
        float psi2 = 0.f, r2 = 0.f, rd2 = 0.f;
        if (p2 < npairs) {
            const int b2 = (2 * p2 + half) * 96 + i;
            psi2 = states[b2]; r2 = states[b2 + 32]; rd2 = states[b2 + 64];
        }

        float s, c;
        __sincosf(psi0, &s, &c);
        const unsigned myuv = pack_rtz(r0 * s, r0 * c);   // {u_i, v_i} f16x2

        float P = 0.f, Q = 0.f;
#pragma unroll
        for (int j = 0; j < NN; j += 4) {
            const unsigned q0 = (unsigned)__builtin_amdgcn_ds_bpermute(permbase + 4 * j,       (int)myuv);
            const unsigned q1 = (unsigned)__builtin_amdgcn_ds_bpermute(permbase + 4 * (j + 1), (int)myuv);
            const unsigned q2 = (unsigned)__builtin_amdgcn_ds_bpermute(permbase + 4 * (j + 2), (int)myuv);
            const unsigned q3 = (unsigned)__builtin_amdgcn_ds_bpermute(permbase + 4 * (j + 3), (int)myuv);
            P = __builtin_amdgcn_fdot2(as_h2(q0), as_h2(Wp[j]),     P, false);
            Q = __builtin_amdgcn_fdot2(as_h2(q0), as_h2(Wq[j]),     Q, false);
            P = __builtin_amdgcn_fdot2(as_h2(q1), as_h2(Wp[j + 1]), P, false);
            Q = __builtin_amdgcn_fdot2(as_h2(q1), as_h2(Wq[j + 1]), Q, false);
            P = __builtin_amdgcn_fdot2(as_h2(q2), as_h2(Wp[j + 2]), P, false);
            Q = __builtin_amdgcn_fdot2(as_h2(q2), as_h2(Wq[j + 2]), Q, false);
            P = __builtin_amdgcn_fdot2(as_h2(q3), as_h2(Wp[j + 3]), P, false);
            Q = __builtin_amdgcn_fdot2(as_h2(q3), as_h2(Wq[j + 3]), Q, false);
        }

        const int ob = (2 * p + half) * 96 + i;
        out[ob]      = fmaf(c, P, fmaf(-s, Q, va2pi));    // psi_dot
        out[ob + 32] = rd0;                               // r_d passthrough
        out[ob + 64] = fmaf(K2, r0, fmaf(K3, rd0, K1));   // r_d_dot

        psi0 = psi1; r0 = r1; rd0 = rd1;                  // rotate pipeline
        psi1 = psi2; r1 = r2; rd1 = rd2;
    }
}

extern "C" void kernel_launch(void* const* d_in, const int* in_sizes, int n_in,
                              void* d_out, int out_size, void* d_ws, size_t ws_size,
                              hipStream_t stream) {
    const float* states = (const float*)d_in[0];
    const float* v      = (const float*)d_in[1];
    const float* b      = (const float*)d_in[2];
    const float* c      = (const float*)d_in[3];
    const float* w      = (const float*)d_in[4];
    const float* phi    = (const float*)d_in[5];
    float* out = (float*)d_out;

    const int B = in_sizes[0] / 96;            // 65536
    const int npairs = B / 2;                  // 32768

    // 1024 blocks * 4 waves = 4096 waves = 4 waves/SIMD resident; 8 pairs/wave
    hopf_kernel<<<1024, 256, 0, stream>>>(states, v, b, c, w, phi, out, npairs);
}